// Round 2
// baseline (197.601 us; speedup 1.0000x reference)
//
#include <hip/hip_runtime.h>
#include <hip/hip_bf16.h>

typedef unsigned short u16;
typedef __attribute__((ext_vector_type(4))) float f32x4;

// ---------------- workspace layout (fp32 elements) ----------------
constexpr int WSF_PRE1 = 0;        // 512   attention query (conv3 out)
constexpr int WSF_LOGA = 512;      // 2048  attention logits
constexpr int WSF_PART = 2560;     // 16*1024 partial e·enc sums
constexpr int WSF_SUME = 18944;    // 1     sum of exp (attention softmax)
constexpr int WSF_XT   = 18960;    // 5*512 xt chain: conv6 out, then per GRU layer
constexpr int WSF_LOGV = 21520;    // 50257 vocab logits
constexpr int WSF_PM   = 71792;    // 786   per-block max
constexpr int WSF_PS   = 72592;    // 786   per-block sum-exp
constexpr int WSF_LSE  = 73392;    // 1
constexpr int NVOCAB   = 50257;
constexpr int NBLK_V   = 786;      // ceil(50257/64)

__device__ __forceinline__ float b2f(u16 u) {
    union { unsigned int i; float f; } v; v.i = ((unsigned int)u) << 16; return v.f;
}
__device__ __forceinline__ u16 f2bu(float f) {
    __hip_bfloat16 h = __float2bfloat16(f);
    return *reinterpret_cast<u16*>(&h);
}
__device__ __forceinline__ float wave_rsum(float v) {
#pragma unroll
    for (int o = 32; o > 0; o >>= 1) v += __shfl_down(v, o);
    return v; // lane 0 holds sum
}
__device__ __forceinline__ float sigm(float x) { return 1.0f / (1.0f + __expf(-x)); }

// =====================================================================
// K1: pre-attention conv stack.  1 block x 512 threads (thread = position)
// =====================================================================
__global__ __launch_bounds__(512) void k_pre(
    const float* __restrict__ emb, const int* __restrict__ xidx,
    const float* __restrict__ hstate,
    const float* __restrict__ w1, const float* __restrict__ b1,
    const float* __restrict__ w2, const float* __restrict__ b2,
    const float* __restrict__ w3, const float* __restrict__ b3,
    const float* __restrict__ g1, const float* __restrict__ bb1,
    const float* __restrict__ g2, const float* __restrict__ bb2,
    const float* __restrict__ g3, const float* __restrict__ bb3,
    float* __restrict__ ws)
{
    constexpr int W1 = 0, B1 = 480, G1 = 512, BB1 = 544;
    constexpr int W2 = 576, B2 = 1056, G2 = 1061, BB2 = 1066;
    constexpr int W3 = 1071, B3 = 1086, G3 = 1087, BB3 = 1088, NW = 1089;
    __shared__ float s_w[NW];
    __shared__ float s_pre[5][512];
    __shared__ u16   s_c[32][512];
    __shared__ float s_r1[32][8];
    __shared__ float s_r2[32][8];

    const int tid = threadIdx.x;
    const int lane = tid & 63, wid = tid >> 6;
    const int l = tid;

    // stage small params to LDS
    if (tid < 480) s_w[W1 + tid] = w1[tid];
    if (tid < 32) { s_w[B1 + tid] = b1[tid]; s_w[G1 + tid] = g1[tid]; s_w[BB1 + tid] = bb1[tid]; }
    if (tid < 480) s_w[W2 + tid] = w2[tid];
    if (tid < 5) { s_w[B2 + tid] = b2[tid]; s_w[G2 + tid] = g2[tid]; s_w[BB2 + tid] = bb2[tid]; }
    if (tid < 15) s_w[W3 + tid] = w3[tid];
    if (tid == 0) { s_w[B3] = b3[0]; s_w[G3] = g3[0]; s_w[BB3] = bb3[0]; }

    const int x = xidx[0];
#pragma unroll
    for (int c = 0; c < 4; ++c) s_pre[c][l] = hstate[c * 512 + l];
    s_pre[4][l] = emb[(size_t)x * 512 + l];
    __syncthreads();

    // ---- conv1 (5->32) ----
    float px[5][3];
#pragma unroll
    for (int ic = 0; ic < 5; ++ic) {
        px[ic][0] = (l > 0)   ? s_pre[ic][l - 1] : 0.0f;
        px[ic][1] =             s_pre[ic][l];
        px[ic][2] = (l < 511) ? s_pre[ic][l + 1] : 0.0f;
    }
    float y[32];
#pragma unroll
    for (int oc = 0; oc < 32; ++oc) {
        float a = s_w[B1 + oc];
#pragma unroll
        for (int ic = 0; ic < 5; ++ic)
#pragma unroll
            for (int k = 0; k < 3; ++k)
                a += s_w[W1 + (oc * 5 + ic) * 3 + k] * px[ic][k];
        y[oc] = a;
        float s = wave_rsum(a);
        float s2 = wave_rsum(a * a);
        if (lane == 0) { s_r1[oc][wid] = s; s_r2[oc][wid] = s2; }
    }
    __syncthreads();
#pragma unroll
    for (int oc = 0; oc < 32; ++oc) {
        float sum = 0.f, sum2 = 0.f;
#pragma unroll
        for (int w = 0; w < 8; ++w) { sum += s_r1[oc][w]; sum2 += s_r2[oc][w]; }
        float m = sum * (1.0f / 512.0f);
        float v = sum2 * (1.0f / 512.0f) - m * m;
        float val = (y[oc] - m) * rsqrtf(v + 1e-5f) * s_w[G1 + oc] + s_w[BB1 + oc];
        s_c[oc][l] = f2bu(fmaxf(val, 0.0f));
    }
    __syncthreads();

    // ---- conv2 (32->5) + residual ----
    float y2[5];
#pragma unroll
    for (int oc = 0; oc < 5; ++oc) y2[oc] = s_w[B2 + oc];
    for (int ic = 0; ic < 32; ++ic) {
        float c0 = (l > 0)   ? b2f(s_c[ic][l - 1]) : 0.0f;
        float c1 =             b2f(s_c[ic][l]);
        float c2 = (l < 511) ? b2f(s_c[ic][l + 1]) : 0.0f;
#pragma unroll
        for (int oc = 0; oc < 5; ++oc) {
            const int base = W2 + (oc * 32 + ic) * 3;
            y2[oc] += s_w[base] * c0 + s_w[base + 1] * c1 + s_w[base + 2] * c2;
        }
    }
#pragma unroll
    for (int oc = 0; oc < 5; ++oc) {
        y2[oc] += s_pre[oc][l];                       // residual (reads old s_pre)
        float s = wave_rsum(y2[oc]);
        float s2 = wave_rsum(y2[oc] * y2[oc]);
        if (lane == 0) { s_r1[oc][wid] = s; s_r2[oc][wid] = s2; }
    }
    __syncthreads();                                   // all old-s_pre reads done
#pragma unroll
    for (int oc = 0; oc < 5; ++oc) {
        float sum = 0.f, sum2 = 0.f;
#pragma unroll
        for (int w = 0; w < 8; ++w) { sum += s_r1[oc][w]; sum2 += s_r2[oc][w]; }
        float m = sum * (1.0f / 512.0f);
        float v = sum2 * (1.0f / 512.0f) - m * m;
        s_pre[oc][l] = fmaxf((y2[oc] - m) * rsqrtf(v + 1e-5f) * s_w[G2 + oc] + s_w[BB2 + oc], 0.0f);
    }
    __syncthreads();

    // ---- conv3 (5->1) ----
    float a3 = s_w[B3];
#pragma unroll
    for (int ic = 0; ic < 5; ++ic) {
        float c0 = (l > 0)   ? s_pre[ic][l - 1] : 0.0f;
        float c1 =             s_pre[ic][l];
        float c2 = (l < 511) ? s_pre[ic][l + 1] : 0.0f;
        const int base = W3 + ic * 3;
        a3 += s_w[base] * c0 + s_w[base + 1] * c1 + s_w[base + 2] * c2;
    }
    {
        float s = wave_rsum(a3);
        float s2 = wave_rsum(a3 * a3);
        if (lane == 0) { s_r1[0][wid] = s; s_r2[0][wid] = s2; }
    }
    __syncthreads();
    {
        float sum = 0.f, sum2 = 0.f;
#pragma unroll
        for (int w = 0; w < 8; ++w) { sum += s_r1[0][w]; sum2 += s_r2[0][w]; }
        float m = sum * (1.0f / 512.0f);
        float v = sum2 * (1.0f / 512.0f) - m * m;
        float val = (a3 - m) * rsqrtf(v + 1e-5f) * s_w[G3] + s_w[BB3];
        ws[WSF_PRE1 + l] = fmaxf(val, 0.0f);
    }
}

// =====================================================================
// K2a: attention logits.  wave-per-row, 4 rows/wave, 128 blocks x 256
// =====================================================================
__global__ __launch_bounds__(256) void k_attlogit(
    const float* __restrict__ attw, const float* __restrict__ attb,
    float* __restrict__ ws)
{
    const int tid = threadIdx.x, lane = tid & 63, wid = tid >> 6;
    float q0[4], q1[4];
#pragma unroll
    for (int j = 0; j < 4; ++j) {
        q0[j] = ws[WSF_PRE1 + lane * 4 + j];
        q1[j] = ws[WSF_PRE1 + 256 + lane * 4 + j];
    }
    const int row0 = (blockIdx.x * 4 + wid) * 4;
#pragma unroll
    for (int r = 0; r < 4; ++r) {
        const int row = row0 + r;
        f32x4 w0 = *reinterpret_cast<const f32x4*>(attw + (size_t)row * 512 + lane * 4);
        f32x4 w1 = *reinterpret_cast<const f32x4*>(attw + (size_t)row * 512 + 256 + lane * 4);
        float a = 0.f;
#pragma unroll
        for (int j = 0; j < 4; ++j) a += w0[j] * q0[j] + w1[j] * q1[j];
        a = wave_rsum(a);
        if (lane == 0) ws[WSF_LOGA + row] = a + attb[row];
    }
}

// =====================================================================
// K2b: softmax (redundant per block, deterministic) + partial e·enc
// grid = 32 blocks (16 j-chunks x 2 column halves), 256 threads
// =====================================================================
__global__ __launch_bounds__(256) void k_attpv(
    const float* __restrict__ enc, float* __restrict__ ws)
{
    __shared__ float s_e[2048];
    __shared__ float s_r[256];
    const int tid = threadIdx.x;
#pragma unroll
    for (int k = 0; k < 8; ++k) s_e[tid + k * 256] = ws[WSF_LOGA + tid + k * 256];
    __syncthreads();
    float m = -INFINITY;
#pragma unroll
    for (int k = 0; k < 8; ++k) m = fmaxf(m, s_e[tid + k * 256]);
    s_r[tid] = m; __syncthreads();
    for (int s = 128; s > 0; s >>= 1) {
        if (tid < s) s_r[tid] = fmaxf(s_r[tid], s_r[tid + s]);
        __syncthreads();
    }
    const float M = s_r[0];
    __syncthreads();
    float t = 0.f;
#pragma unroll
    for (int k = 0; k < 8; ++k) {
        const int i = tid + k * 256;
        float e = __expf(s_e[i] - M);
        s_e[i] = e;
        t += e;
    }
    s_r[tid] = t; __syncthreads();
    for (int s = 128; s > 0; s >>= 1) {
        if (tid < s) s_r[tid] += s_r[tid + s];
        __syncthreads();
    }
    const float S = s_r[0];
    if (blockIdx.x == 0 && tid == 0) ws[WSF_SUME] = S;

    const int jc = blockIdx.x >> 1, half = blockIdx.x & 1;
    const int col = half * 512 + tid * 2;
    const float* ep = enc + (size_t)(jc * 128) * 1024 + col;
    float a0 = 0.f, a1 = 0.f;
#pragma unroll 4
    for (int jj = 0; jj < 128; ++jj) {
        const float w = s_e[jc * 128 + jj];
        float2 e = *reinterpret_cast<const float2*>(ep + (size_t)jj * 1024);
        a0 += w * e.x;
        a1 += w * e.y;
    }
    ws[WSF_PART + jc * 1024 + col]     = a0;
    ws[WSF_PART + jc * 1024 + col + 1] = a1;
}

// =====================================================================
// K3: post-attention conv stack.  1 block x 512 threads
// =====================================================================
__global__ __launch_bounds__(512) void k_post(
    const float* __restrict__ emb, const int* __restrict__ xidx,
    const float* __restrict__ w4, const float* __restrict__ b4,
    const float* __restrict__ w5, const float* __restrict__ b5,
    const float* __restrict__ w6, const float* __restrict__ b6,
    const float* __restrict__ g4, const float* __restrict__ bb4,
    const float* __restrict__ g5, const float* __restrict__ bb5,
    const float* __restrict__ g6, const float* __restrict__ bb6,
    float* __restrict__ ws)
{
    constexpr int W4 = 0, B4 = 288, G4 = 320, BB4 = 352;
    constexpr int W5 = 384, B5 = 672, G5 = 675, BB5 = 678;
    constexpr int W6 = 681, B6 = 690, G6 = 691, BB6 = 692, NW = 693;
    __shared__ float s_w[NW];
    __shared__ float s_com[3][512];
    __shared__ u16   s_c[32][512];
    __shared__ float s_r1[32][8];
    __shared__ float s_r2[32][8];

    const int tid = threadIdx.x;
    const int lane = tid & 63, wid = tid >> 6;
    const int l = tid;

    if (tid < 288) s_w[W4 + tid] = w4[tid];
    if (tid < 32) { s_w[B4 + tid] = b4[tid]; s_w[G4 + tid] = g4[tid]; s_w[BB4 + tid] = bb4[tid]; }
    if (tid < 288) s_w[W5 + tid] = w5[tid];
    if (tid < 3) { s_w[B5 + tid] = b5[tid]; s_w[G5 + tid] = g5[tid]; s_w[BB5 + tid] = bb5[tid]; }
    if (tid < 9) s_w[W6 + tid] = w6[tid];
    if (tid == 0) { s_w[B6] = b6[0]; s_w[G6] = g6[0]; s_w[BB6] = bb6[0]; }

    // app = (sum of partials)/S ; com = concat(app0, app1, emb)
    const float invS = 1.0f / ws[WSF_SUME];
    float a0 = 0.f, a1 = 0.f;
#pragma unroll
    for (int p = 0; p < 16; ++p) {
        a0 += ws[WSF_PART + p * 1024 + l];
        a1 += ws[WSF_PART + p * 1024 + 512 + l];
    }
    const int x = xidx[0];
    s_com[0][l] = a0 * invS;
    s_com[1][l] = a1 * invS;
    s_com[2][l] = emb[(size_t)x * 512 + l];
    __syncthreads();

    // ---- conv4 (3->32) ----
    float px[3][3];
#pragma unroll
    for (int ic = 0; ic < 3; ++ic) {
        px[ic][0] = (l > 0)   ? s_com[ic][l - 1] : 0.0f;
        px[ic][1] =             s_com[ic][l];
        px[ic][2] = (l < 511) ? s_com[ic][l + 1] : 0.0f;
    }
    float y[32];
#pragma unroll
    for (int oc = 0; oc < 32; ++oc) {
        float a = s_w[B4 + oc];
#pragma unroll
        for (int ic = 0; ic < 3; ++ic)
#pragma unroll
            for (int k = 0; k < 3; ++k)
                a += s_w[W4 + (oc * 3 + ic) * 3 + k] * px[ic][k];
        y[oc] = a;
        float s = wave_rsum(a);
        float s2 = wave_rsum(a * a);
        if (lane == 0) { s_r1[oc][wid] = s; s_r2[oc][wid] = s2; }
    }
    __syncthreads();
#pragma unroll
    for (int oc = 0; oc < 32; ++oc) {
        float sum = 0.f, sum2 = 0.f;
#pragma unroll
        for (int w = 0; w < 8; ++w) { sum += s_r1[oc][w]; sum2 += s_r2[oc][w]; }
        float m = sum * (1.0f / 512.0f);
        float v = sum2 * (1.0f / 512.0f) - m * m;
        float val = (y[oc] - m) * rsqrtf(v + 1e-5f) * s_w[G4 + oc] + s_w[BB4 + oc];
        s_c[oc][l] = f2bu(fmaxf(val, 0.0f));
    }
    __syncthreads();

    // ---- conv5 (32->3) + residual ----
    float y2[3];
#pragma unroll
    for (int oc = 0; oc < 3; ++oc) y2[oc] = s_w[B5 + oc];
    for (int ic = 0; ic < 32; ++ic) {
        float c0 = (l > 0)   ? b2f(s_c[ic][l - 1]) : 0.0f;
        float c1 =             b2f(s_c[ic][l]);
        float c2 = (l < 511) ? b2f(s_c[ic][l + 1]) : 0.0f;
#pragma unroll
        for (int oc = 0; oc < 3; ++oc) {
            const int base = W5 + (oc * 32 + ic) * 3;
            y2[oc] += s_w[base] * c0 + s_w[base + 1] * c1 + s_w[base + 2] * c2;
        }
    }
#pragma unroll
    for (int oc = 0; oc < 3; ++oc) {
        y2[oc] += s_com[oc][l];
        float s = wave_rsum(y2[oc]);
        float s2 = wave_rsum(y2[oc] * y2[oc]);
        if (lane == 0) { s_r1[oc][wid] = s; s_r2[oc][wid] = s2; }
    }
    __syncthreads();
#pragma unroll
    for (int oc = 0; oc < 3; ++oc) {
        float sum = 0.f, sum2 = 0.f;
#pragma unroll
        for (int w = 0; w < 8; ++w) { sum += s_r1[oc][w]; sum2 += s_r2[oc][w]; }
        float m = sum * (1.0f / 512.0f);
        float v = sum2 * (1.0f / 512.0f) - m * m;
        s_com[oc][l] = fmaxf((y2[oc] - m) * rsqrtf(v + 1e-5f) * s_w[G5 + oc] + s_w[BB5 + oc], 0.0f);
    }
    __syncthreads();

    // ---- conv6 (3->1) ----
    float a6 = s_w[B6];
#pragma unroll
    for (int ic = 0; ic < 3; ++ic) {
        float c0 = (l > 0)   ? s_com[ic][l - 1] : 0.0f;
        float c1 =             s_com[ic][l];
        float c2 = (l < 511) ? s_com[ic][l + 1] : 0.0f;
        const int base = W6 + ic * 3;
        a6 += s_w[base] * c0 + s_w[base + 1] * c1 + s_w[base + 2] * c2;
    }
    {
        float s = wave_rsum(a6);
        float s2 = wave_rsum(a6 * a6);
        if (lane == 0) { s_r1[0][wid] = s; s_r2[0][wid] = s2; }
    }
    __syncthreads();
    {
        float sum = 0.f, sum2 = 0.f;
#pragma unroll
        for (int w = 0; w < 8; ++w) { sum += s_r1[0][w]; sum2 += s_r2[0][w]; }
        float m = sum * (1.0f / 512.0f);
        float v = sum2 * (1.0f / 512.0f) - m * m;
        float val = (a6 - m) * rsqrtf(v + 1e-5f) * s_w[G6] + s_w[BB6];
        ws[WSF_XT + l] = fmaxf(val, 0.0f);
    }
}

// =====================================================================
// K4: one GRU layer.  64 blocks x 256 threads; block owns 8 hidden units,
// computes all 6 GEMV rows per unit locally (no grid sync needed).
// =====================================================================
__global__ __launch_bounds__(256) void k_gru(
    const float* __restrict__ wih, const float* __restrict__ whh,
    const float* __restrict__ bih, const float* __restrict__ bhh,
    const float* __restrict__ hstate,
    const float* __restrict__ xt_in, float* __restrict__ xt_out,
    float* __restrict__ hout, int layer)
{
    wih += (size_t)layer * 1536 * 512;
    whh += (size_t)layer * 1536 * 512;
    bih += layer * 1536;
    bhh += layer * 1536;
    const float* hp = hstate + layer * 512;

    const int tid = threadIdx.x, lane = tid & 63, wid = tid >> 6;
    float xq0[4], xq1[4], hq0[4], hq1[4];
#pragma unroll
    for (int j = 0; j < 4; ++j) {
        xq0[j] = xt_in[lane * 4 + j];
        xq1[j] = xt_in[256 + lane * 4 + j];
        hq0[j] = hp[lane * 4 + j];
        hq1[j] = hp[256 + lane * 4 + j];
    }
    __shared__ float s_g[8][6];
    const int i0 = blockIdx.x * 8;
#pragma unroll
    for (int t = 0; t < 2; ++t) {
        const int ii = wid * 2 + t;
        const int i = i0 + ii;
        float a[6] = {0.f, 0.f, 0.f, 0.f, 0.f, 0.f};
#pragma unroll
        for (int g = 0; g < 3; ++g) {
            const float* wr = wih + (size_t)(i + g * 512) * 512;
            f32x4 w0 = *reinterpret_cast<const f32x4*>(wr + lane * 4);
            f32x4 w1 = *reinterpret_cast<const f32x4*>(wr + 256 + lane * 4);
#pragma unroll
            for (int j = 0; j < 4; ++j) a[g] += w0[j] * xq0[j] + w1[j] * xq1[j];
        }
#pragma unroll
        for (int g = 0; g < 3; ++g) {
            const float* wr = whh + (size_t)(i + g * 512) * 512;
            f32x4 w0 = *reinterpret_cast<const f32x4*>(wr + lane * 4);
            f32x4 w1 = *reinterpret_cast<const f32x4*>(wr + 256 + lane * 4);
#pragma unroll
            for (int j = 0; j < 4; ++j) a[3 + g] += w0[j] * hq0[j] + w1[j] * hq1[j];
        }
#pragma unroll
        for (int g = 0; g < 6; ++g) a[g] = wave_rsum(a[g]);
        if (lane == 0) {
#pragma unroll
            for (int g = 0; g < 6; ++g) s_g[ii][g] = a[g];
        }
    }
    __syncthreads();
    if (tid < 8) {
        const int i = i0 + tid;
        float ir = s_g[tid][0] + bih[i];
        float iz = s_g[tid][1] + bih[i + 512];
        float in_ = s_g[tid][2] + bih[i + 1024];
        float hr = s_g[tid][3] + bhh[i];
        float hz = s_g[tid][4] + bhh[i + 512];
        float hn = s_g[tid][5] + bhh[i + 1024];
        float r = sigm(ir + hr);
        float z = sigm(iz + hz);
        float n = tanhf(in_ + r * hn);
        float hprev = hp[i];
        float h = (1.0f - z) * n + z * hprev;
        xt_out[i] = h;
        hout[i] = h;
    }
}

// =====================================================================
// K5: vocab GEMV + per-block online (max, sum-exp).  786 blocks x 256
// =====================================================================
__global__ __launch_bounds__(256) void k_vocab(
    const float* __restrict__ low, const float* __restrict__ lob,
    float* __restrict__ ws)
{
    const int tid = threadIdx.x, lane = tid & 63, wid = tid >> 6;
    float q0[4], q1[4];
#pragma unroll
    for (int j = 0; j < 4; ++j) {
        q0[j] = ws[WSF_XT + 4 * 512 + lane * 4 + j];
        q1[j] = ws[WSF_XT + 4 * 512 + 256 + lane * 4 + j];
    }

    const int row0 = blockIdx.x * 64 + wid * 16;
    float m = -INFINITY, s = 0.0f;
#pragma unroll 4
    for (int r = 0; r < 16; ++r) {
        const int row = row0 + r;
        if (row < NVOCAB) {
            f32x4 w0 = *reinterpret_cast<const f32x4*>(low + (size_t)row * 512 + lane * 4);
            f32x4 w1 = *reinterpret_cast<const f32x4*>(low + (size_t)row * 512 + 256 + lane * 4);
            float a = 0.f;
#pragma unroll
            for (int j = 0; j < 4; ++j) a += w0[j] * q0[j] + w1[j] * q1[j];
            a = wave_rsum(a);
            if (lane == 0) {
                float v = a + lob[row];
                ws[WSF_LOGV + row] = v;
                if (v > m) { s = s * __expf(m - v) + 1.0f; m = v; }
                else       { s += __expf(v - m); }
            }
        }
    }
    __shared__ float sm[4], ss[4];
    if (lane == 0) { sm[wid] = m; ss[wid] = s; }
    __syncthreads();
    if (tid == 0) {
        float M = -INFINITY, S = 0.0f;
#pragma unroll
        for (int w = 0; w < 4; ++w) {
            float mb = sm[w], sb = ss[w];
            if (sb > 0.0f) {
                if (mb > M) { S = S * __expf(M - mb) + sb; M = mb; }
                else        { S += sb * __expf(mb - M); }
            }
        }
        ws[WSF_PM + blockIdx.x] = M;
        ws[WSF_PS + blockIdx.x] = S;
    }
}

// =====================================================================
// K6: combine per-block (max, sum-exp) -> logsumexp.  1 block x 256
// =====================================================================
__global__ __launch_bounds__(256) void k_lse(float* __restrict__ ws, int nb)
{
    __shared__ float sm[256], ss[256];
    const int tid = threadIdx.x;
    float M = -INFINITY, S = 0.0f;
    for (int i = tid; i < nb; i += 256) {
        float mb = ws[WSF_PM + i], sb = ws[WSF_PS + i];
        if (sb > 0.0f) {
            if (mb > M) { S = S * __expf(M - mb) + sb; M = mb; }
            else        { S += sb * __expf(mb - M); }
        }
    }
    sm[tid] = M; ss[tid] = S;
    __syncthreads();
    for (int st = 128; st > 0; st >>= 1) {
        if (tid < st) {
            float mb = sm[tid + st], sb = ss[tid + st];
            if (sb > 0.0f) {
                if (mb > sm[tid]) { ss[tid] = ss[tid] * __expf(sm[tid] - mb) + sb; sm[tid] = mb; }
                else              { ss[tid] += sb * __expf(mb - sm[tid]); }
            }
        }
        __syncthreads();
    }
    if (tid == 0) ws[WSF_LSE] = sm[0] + logf(ss[0]);
}

// =====================================================================
// K7: write log-probs
// =====================================================================
__global__ __launch_bounds__(256) void k_out(
    const float* __restrict__ ws, float* __restrict__ out)
{
    const int i = blockIdx.x * 256 + threadIdx.x;
    if (i < NVOCAB) out[i] = ws[WSF_LOGV + i] - ws[WSF_LSE];
}

// =====================================================================
extern "C" void kernel_launch(void* const* d_in, const int* in_sizes, int n_in,
                              void* d_out, int out_size, void* d_ws, size_t ws_size,
                              hipStream_t stream)
{
    (void)in_sizes; (void)n_in; (void)out_size; (void)ws_size;
    const float* emb     = (const float*)d_in[0];
    const float* conv1_w = (const float*)d_in[1];  const float* conv1_b = (const float*)d_in[2];
    const float* conv2_w = (const float*)d_in[3];  const float* conv2_b = (const float*)d_in[4];
    const float* conv3_w = (const float*)d_in[5];  const float* conv3_b = (const float*)d_in[6];
    const float* conv4_w = (const float*)d_in[7];  const float* conv4_b = (const float*)d_in[8];
    const float* conv5_w = (const float*)d_in[9];  const float* conv5_b = (const float*)d_in[10];
    const float* conv6_w = (const float*)d_in[11]; const float* conv6_b = (const float*)d_in[12];
    const float* bn1_g = (const float*)d_in[13];   const float* bn1_b = (const float*)d_in[14];
    const float* bn2_g = (const float*)d_in[15];   const float* bn2_b = (const float*)d_in[16];
    const float* bn3_g = (const float*)d_in[17];   const float* bn3_b = (const float*)d_in[18];
    const float* bn4_g = (const float*)d_in[19];   const float* bn4_b = (const float*)d_in[20];
    const float* bn5_g = (const float*)d_in[21];   const float* bn5_b = (const float*)d_in[22];
    const float* bn6_g = (const float*)d_in[23];   const float* bn6_b = (const float*)d_in[24];
    const float* att_w = (const float*)d_in[25];   const float* att_b = (const float*)d_in[26];
    const float* gru_wih = (const float*)d_in[27]; const float* gru_whh = (const float*)d_in[28];
    const float* gru_bih = (const float*)d_in[29]; const float* gru_bhh = (const float*)d_in[30];
    const float* lo_w = (const float*)d_in[31];    const float* lo_b = (const float*)d_in[32];
    const float* h_state = (const float*)d_in[33];
    const float* enc = (const float*)d_in[34];
    const int* x = (const int*)d_in[35];

    float* ws = (float*)d_ws;
    float* out = (float*)d_out;

    k_pre<<<1, 512, 0, stream>>>(emb, x, h_state,
        conv1_w, conv1_b, conv2_w, conv2_b, conv3_w, conv3_b,
        bn1_g, bn1_b, bn2_g, bn2_b, bn3_g, bn3_b, ws);
    k_attlogit<<<128, 256, 0, stream>>>(att_w, att_b, ws);
    k_attpv<<<32, 256, 0, stream>>>(enc, ws);
    k_post<<<1, 512, 0, stream>>>(emb, x,
        conv4_w, conv4_b, conv5_w, conv5_b, conv6_w, conv6_b,
        bn4_g, bn4_b, bn5_g, bn5_b, bn6_g, bn6_b, ws);
    for (int l = 0; l < 4; ++l) {
        k_gru<<<64, 256, 0, stream>>>(gru_wih, gru_whh, gru_bih, gru_bhh, h_state,
            ws + WSF_XT + l * 512, ws + WSF_XT + (l + 1) * 512,
            out + NVOCAB + l * 512, l);
    }
    k_vocab<<<NBLK_V, 256, 0, stream>>>(lo_w, lo_b, ws);
    k_lse<<<1, 256, 0, stream>>>(ws, NBLK_V);
    k_out<<<197, 256, 0, stream>>>(ws, out);
}

// Round 3
// 100.361 us; speedup vs baseline: 1.9689x; 1.9689x over previous
//
#include <hip/hip_runtime.h>
#include <hip/hip_bf16.h>

typedef __attribute__((ext_vector_type(4))) float f32x4;

// ---------------- workspace layout (fp32 elements) ----------------
constexpr int WSF_PRE1 = 0;        // 512   attention query (conv3 out)
constexpr int WSF_LOGA = 512;      // 2048  attention logits
constexpr int WSF_PART = 2560;     // 16*1024 partial e·enc sums
constexpr int WSF_SUME = 18944;    // 1     sum of exp (attention softmax)
constexpr int WSF_XT   = 18960;    // 5*512 xt chain: conv6 out, then per GRU layer
constexpr int WSF_LOGV = 21520;    // 50257 vocab logits
constexpr int WSF_PM   = 71792;    // 786   per-block max
constexpr int WSF_PS   = 72592;    // 786   per-block sum-exp
constexpr int WSF_LSE  = 73392;    // 1
constexpr int NVOCAB   = 50257;
constexpr int NBLK_V   = 786;      // ceil(50257/64)

__device__ __forceinline__ float wave_rsum(float v) {
#pragma unroll
    for (int o = 32; o > 0; o >>= 1) v += __shfl_down(v, o);
    return v; // lane 0 holds sum
}
__device__ __forceinline__ float sigm(float x) { return 1.0f / (1.0f + __expf(-x)); }

// =====================================================================
// K1: pre-attention conv stack.  1 block x 512 threads (thread = position)
// Rolled loops + LDS-resident pre-BN activations: tiny register pressure,
// tiny code, wave-per-channel BN stats.
// =====================================================================
__global__ __launch_bounds__(512) void k_pre(
    const float* __restrict__ emb, const int* __restrict__ xidx,
    const float* __restrict__ hstate,
    const float* __restrict__ w1, const float* __restrict__ b1,
    const float* __restrict__ w2, const float* __restrict__ b2,
    const float* __restrict__ w3, const float* __restrict__ b3,
    const float* __restrict__ g1, const float* __restrict__ bb1,
    const float* __restrict__ g2, const float* __restrict__ bb2,
    const float* __restrict__ g3, const float* __restrict__ bb3,
    float* __restrict__ ws)
{
    constexpr int W1 = 0, B1 = 480, G1 = 512, BB1 = 544;
    constexpr int W2 = 576, B2 = 1056, G2 = 1061, BB2 = 1066;
    constexpr int W3 = 1071, B3 = 1086, G3 = 1087, BB3 = 1088, NW = 1089;
    __shared__ float s_w[NW];
    __shared__ float s_pre[5][512];
    __shared__ float s_y[32][512];     // pre-BN conv1 output (64 KB)
    __shared__ float s_stat[32][2];    // per-channel mean, rstd

    const int tid = threadIdx.x;
    const int lane = tid & 63, wid = tid >> 6;
    const int l = tid;

    if (tid < 480) s_w[W1 + tid] = w1[tid];
    if (tid < 32) { s_w[B1 + tid] = b1[tid]; s_w[G1 + tid] = g1[tid]; s_w[BB1 + tid] = bb1[tid]; }
    if (tid < 480) s_w[W2 + tid] = w2[tid];
    if (tid < 5) { s_w[B2 + tid] = b2[tid]; s_w[G2 + tid] = g2[tid]; s_w[BB2 + tid] = bb2[tid]; }
    if (tid < 15) s_w[W3 + tid] = w3[tid];
    if (tid == 0) { s_w[B3] = b3[0]; s_w[G3] = g3[0]; s_w[BB3] = bb3[0]; }

    const int x = xidx[0];
#pragma unroll
    for (int c = 0; c < 4; ++c) s_pre[c][l] = hstate[c * 512 + l];
    s_pre[4][l] = emb[(size_t)x * 512 + l];
    __syncthreads();

    // ---- conv1 (5->32): write pre-BN to LDS ----
    float px[5][3];
#pragma unroll
    for (int ic = 0; ic < 5; ++ic) {
        px[ic][0] = (l > 0)   ? s_pre[ic][l - 1] : 0.0f;
        px[ic][1] =             s_pre[ic][l];
        px[ic][2] = (l < 511) ? s_pre[ic][l + 1] : 0.0f;
    }
#pragma unroll 4
    for (int oc = 0; oc < 32; ++oc) {
        float a = s_w[B1 + oc];
#pragma unroll
        for (int ic = 0; ic < 5; ++ic)
#pragma unroll
            for (int k = 0; k < 3; ++k)
                a += s_w[W1 + oc * 15 + ic * 3 + k] * px[ic][k];
        s_y[oc][l] = a;
    }
    __syncthreads();

    // ---- BN1 stats: wave w reduces channels 4w..4w+3 over all 512 ----
#pragma unroll
    for (int t = 0; t < 4; ++t) {
        const int oc = wid * 4 + t;
        float s = 0.f, s2 = 0.f;
#pragma unroll
        for (int j = 0; j < 8; ++j) {
            float v = s_y[oc][lane + j * 64];
            s += v; s2 += v * v;
        }
        s = wave_rsum(s); s2 = wave_rsum(s2);
        if (lane == 0) {
            float m = s * (1.0f / 512.0f);
            float var = s2 * (1.0f / 512.0f) - m * m;
            s_stat[oc][0] = m; s_stat[oc][1] = rsqrtf(var + 1e-5f);
        }
    }
    __syncthreads();

    // ---- normalize + ReLU in place ----
#pragma unroll 4
    for (int oc = 0; oc < 32; ++oc) {
        float m = s_stat[oc][0], r = s_stat[oc][1];
        s_y[oc][l] = fmaxf((s_y[oc][l] - m) * r * s_w[G1 + oc] + s_w[BB1 + oc], 0.0f);
    }
    __syncthreads();

    // ---- conv2 (32->5) + residual ----
    float y2[5];
#pragma unroll
    for (int oc = 0; oc < 5; ++oc) y2[oc] = s_w[B2 + oc];
#pragma unroll 2
    for (int ic = 0; ic < 32; ++ic) {
        float c0 = (l > 0)   ? s_y[ic][l - 1] : 0.0f;
        float c1 =             s_y[ic][l];
        float c2 = (l < 511) ? s_y[ic][l + 1] : 0.0f;
#pragma unroll
        for (int oc = 0; oc < 5; ++oc) {
            const int base = W2 + (oc * 32 + ic) * 3;
            y2[oc] += s_w[base] * c0 + s_w[base + 1] * c1 + s_w[base + 2] * c2;
        }
    }
#pragma unroll
    for (int oc = 0; oc < 5; ++oc) y2[oc] += s_pre[oc][l];   // residual
    __syncthreads();                                          // conv2 s_y reads done
#pragma unroll
    for (int oc = 0; oc < 5; ++oc) s_y[oc][l] = y2[oc];
    __syncthreads();

    // ---- BN2 stats: waves 0..4, one channel each ----
    if (wid < 5) {
        const int oc = wid;
        float s = 0.f, s2 = 0.f;
#pragma unroll
        for (int j = 0; j < 8; ++j) {
            float v = s_y[oc][lane + j * 64];
            s += v; s2 += v * v;
        }
        s = wave_rsum(s); s2 = wave_rsum(s2);
        if (lane == 0) {
            float m = s * (1.0f / 512.0f);
            float var = s2 * (1.0f / 512.0f) - m * m;
            s_stat[oc][0] = m; s_stat[oc][1] = rsqrtf(var + 1e-5f);
        }
    }
    __syncthreads();
#pragma unroll
    for (int oc = 0; oc < 5; ++oc) {
        float m = s_stat[oc][0], r = s_stat[oc][1];
        s_pre[oc][l] = fmaxf((y2[oc] - m) * r * s_w[G2 + oc] + s_w[BB2 + oc], 0.0f);
    }
    __syncthreads();

    // ---- conv3 (5->1) ----
    float a3 = s_w[B3];
#pragma unroll
    for (int ic = 0; ic < 5; ++ic) {
        float c0 = (l > 0)   ? s_pre[ic][l - 1] : 0.0f;
        float c1 =             s_pre[ic][l];
        float c2 = (l < 511) ? s_pre[ic][l + 1] : 0.0f;
        a3 += s_w[W3 + ic * 3] * c0 + s_w[W3 + ic * 3 + 1] * c1 + s_w[W3 + ic * 3 + 2] * c2;
    }
    s_y[0][l] = a3;
    __syncthreads();
    if (wid == 0) {
        float s = 0.f, s2 = 0.f;
#pragma unroll
        for (int j = 0; j < 8; ++j) {
            float v = s_y[0][lane + j * 64];
            s += v; s2 += v * v;
        }
        s = wave_rsum(s); s2 = wave_rsum(s2);
        if (lane == 0) {
            float m = s * (1.0f / 512.0f);
            float var = s2 * (1.0f / 512.0f) - m * m;
            s_stat[0][0] = m; s_stat[0][1] = rsqrtf(var + 1e-5f);
        }
    }
    __syncthreads();
    ws[WSF_PRE1 + l] = fmaxf((a3 - s_stat[0][0]) * s_stat[0][1] * s_w[G3] + s_w[BB3], 0.0f);
}

// =====================================================================
// K2a: attention logits.  wave-per-row, 4 rows/wave, 128 blocks x 256
// =====================================================================
__global__ __launch_bounds__(256) void k_attlogit(
    const float* __restrict__ attw, const float* __restrict__ attb,
    float* __restrict__ ws)
{
    const int tid = threadIdx.x, lane = tid & 63, wid = tid >> 6;
    float q0[4], q1[4];
#pragma unroll
    for (int j = 0; j < 4; ++j) {
        q0[j] = ws[WSF_PRE1 + lane * 4 + j];
        q1[j] = ws[WSF_PRE1 + 256 + lane * 4 + j];
    }
    const int row0 = (blockIdx.x * 4 + wid) * 4;
#pragma unroll
    for (int r = 0; r < 4; ++r) {
        const int row = row0 + r;
        f32x4 w0 = *reinterpret_cast<const f32x4*>(attw + (size_t)row * 512 + lane * 4);
        f32x4 w1 = *reinterpret_cast<const f32x4*>(attw + (size_t)row * 512 + 256 + lane * 4);
        float a = 0.f;
#pragma unroll
        for (int j = 0; j < 4; ++j) a += w0[j] * q0[j] + w1[j] * q1[j];
        a = wave_rsum(a);
        if (lane == 0) ws[WSF_LOGA + row] = a + attb[row];
    }
}

// =====================================================================
// K2b: softmax (redundant per block, deterministic) + partial e·enc
// grid = 32 blocks (16 j-chunks x 2 column halves), 256 threads
// =====================================================================
__global__ __launch_bounds__(256) void k_attpv(
    const float* __restrict__ enc, float* __restrict__ ws)
{
    __shared__ float s_e[2048];
    __shared__ float s_r[256];
    const int tid = threadIdx.x;
#pragma unroll
    for (int k = 0; k < 8; ++k) s_e[tid + k * 256] = ws[WSF_LOGA + tid + k * 256];
    __syncthreads();
    float m = -INFINITY;
#pragma unroll
    for (int k = 0; k < 8; ++k) m = fmaxf(m, s_e[tid + k * 256]);
    s_r[tid] = m; __syncthreads();
    for (int s = 128; s > 0; s >>= 1) {
        if (tid < s) s_r[tid] = fmaxf(s_r[tid], s_r[tid + s]);
        __syncthreads();
    }
    const float M = s_r[0];
    __syncthreads();
    float t = 0.f;
#pragma unroll
    for (int k = 0; k < 8; ++k) {
        const int i = tid + k * 256;
        float e = __expf(s_e[i] - M);
        s_e[i] = e;
        t += e;
    }
    s_r[tid] = t; __syncthreads();
    for (int s = 128; s > 0; s >>= 1) {
        if (tid < s) s_r[tid] += s_r[tid + s];
        __syncthreads();
    }
    const float S = s_r[0];
    if (blockIdx.x == 0 && tid == 0) ws[WSF_SUME] = S;

    const int jc = blockIdx.x >> 1, half = blockIdx.x & 1;
    const int col = half * 512 + tid * 2;
    const float* ep = enc + (size_t)(jc * 128) * 1024 + col;
    float a0 = 0.f, a1 = 0.f;
#pragma unroll 4
    for (int jj = 0; jj < 128; ++jj) {
        const float w = s_e[jc * 128 + jj];
        float2 e = *reinterpret_cast<const float2*>(ep + (size_t)jj * 1024);
        a0 += w * e.x;
        a1 += w * e.y;
    }
    ws[WSF_PART + jc * 1024 + col]     = a0;
    ws[WSF_PART + jc * 1024 + col + 1] = a1;
}

// =====================================================================
// K3: post-attention conv stack.  1 block x 512 threads (same structure
// as k_pre: rolled loops, LDS pre-BN buffer, wave-per-channel stats)
// =====================================================================
__global__ __launch_bounds__(512) void k_post(
    const float* __restrict__ emb, const int* __restrict__ xidx,
    const float* __restrict__ w4, const float* __restrict__ b4,
    const float* __restrict__ w5, const float* __restrict__ b5,
    const float* __restrict__ w6, const float* __restrict__ b6,
    const float* __restrict__ g4, const float* __restrict__ bb4,
    const float* __restrict__ g5, const float* __restrict__ bb5,
    const float* __restrict__ g6, const float* __restrict__ bb6,
    float* __restrict__ ws)
{
    constexpr int W4 = 0, B4 = 288, G4 = 320, BB4 = 352;
    constexpr int W5 = 384, B5 = 672, G5 = 675, BB5 = 678;
    constexpr int W6 = 681, B6 = 690, G6 = 691, BB6 = 692, NW = 693;
    __shared__ float s_w[NW];
    __shared__ float s_com[3][512];
    __shared__ float s_y[32][512];
    __shared__ float s_stat[32][2];

    const int tid = threadIdx.x;
    const int lane = tid & 63, wid = tid >> 6;
    const int l = tid;

    if (tid < 288) s_w[W4 + tid] = w4[tid];
    if (tid < 32) { s_w[B4 + tid] = b4[tid]; s_w[G4 + tid] = g4[tid]; s_w[BB4 + tid] = bb4[tid]; }
    if (tid < 288) s_w[W5 + tid] = w5[tid];
    if (tid < 3) { s_w[B5 + tid] = b5[tid]; s_w[G5 + tid] = g5[tid]; s_w[BB5 + tid] = bb5[tid]; }
    if (tid < 9) s_w[W6 + tid] = w6[tid];
    if (tid == 0) { s_w[B6] = b6[0]; s_w[G6] = g6[0]; s_w[BB6] = bb6[0]; }

    // app = (sum of partials)/S ; com = concat(app0, app1, emb)
    const float invS = 1.0f / ws[WSF_SUME];
    float a0 = 0.f, a1 = 0.f;
#pragma unroll
    for (int p = 0; p < 16; ++p) {
        a0 += ws[WSF_PART + p * 1024 + l];
        a1 += ws[WSF_PART + p * 1024 + 512 + l];
    }
    const int x = xidx[0];
    s_com[0][l] = a0 * invS;
    s_com[1][l] = a1 * invS;
    s_com[2][l] = emb[(size_t)x * 512 + l];
    __syncthreads();

    // ---- conv4 (3->32) ----
    float px[3][3];
#pragma unroll
    for (int ic = 0; ic < 3; ++ic) {
        px[ic][0] = (l > 0)   ? s_com[ic][l - 1] : 0.0f;
        px[ic][1] =             s_com[ic][l];
        px[ic][2] = (l < 511) ? s_com[ic][l + 1] : 0.0f;
    }
#pragma unroll 4
    for (int oc = 0; oc < 32; ++oc) {
        float a = s_w[B4 + oc];
#pragma unroll
        for (int ic = 0; ic < 3; ++ic)
#pragma unroll
            for (int k = 0; k < 3; ++k)
                a += s_w[W4 + oc * 9 + ic * 3 + k] * px[ic][k];
        s_y[oc][l] = a;
    }
    __syncthreads();

#pragma unroll
    for (int t = 0; t < 4; ++t) {
        const int oc = wid * 4 + t;
        float s = 0.f, s2 = 0.f;
#pragma unroll
        for (int j = 0; j < 8; ++j) {
            float v = s_y[oc][lane + j * 64];
            s += v; s2 += v * v;
        }
        s = wave_rsum(s); s2 = wave_rsum(s2);
        if (lane == 0) {
            float m = s * (1.0f / 512.0f);
            float var = s2 * (1.0f / 512.0f) - m * m;
            s_stat[oc][0] = m; s_stat[oc][1] = rsqrtf(var + 1e-5f);
        }
    }
    __syncthreads();
#pragma unroll 4
    for (int oc = 0; oc < 32; ++oc) {
        float m = s_stat[oc][0], r = s_stat[oc][1];
        s_y[oc][l] = fmaxf((s_y[oc][l] - m) * r * s_w[G4 + oc] + s_w[BB4 + oc], 0.0f);
    }
    __syncthreads();

    // ---- conv5 (32->3) + residual ----
    float y2[3];
#pragma unroll
    for (int oc = 0; oc < 3; ++oc) y2[oc] = s_w[B5 + oc];
#pragma unroll 2
    for (int ic = 0; ic < 32; ++ic) {
        float c0 = (l > 0)   ? s_y[ic][l - 1] : 0.0f;
        float c1 =             s_y[ic][l];
        float c2 = (l < 511) ? s_y[ic][l + 1] : 0.0f;
#pragma unroll
        for (int oc = 0; oc < 3; ++oc) {
            const int base = W5 + (oc * 32 + ic) * 3;
            y2[oc] += s_w[base] * c0 + s_w[base + 1] * c1 + s_w[base + 2] * c2;
        }
    }
#pragma unroll
    for (int oc = 0; oc < 3; ++oc) y2[oc] += s_com[oc][l];
    __syncthreads();
#pragma unroll
    for (int oc = 0; oc < 3; ++oc) s_y[oc][l] = y2[oc];
    __syncthreads();
    if (wid < 3) {
        const int oc = wid;
        float s = 0.f, s2 = 0.f;
#pragma unroll
        for (int j = 0; j < 8; ++j) {
            float v = s_y[oc][lane + j * 64];
            s += v; s2 += v * v;
        }
        s = wave_rsum(s); s2 = wave_rsum(s2);
        if (lane == 0) {
            float m = s * (1.0f / 512.0f);
            float var = s2 * (1.0f / 512.0f) - m * m;
            s_stat[oc][0] = m; s_stat[oc][1] = rsqrtf(var + 1e-5f);
        }
    }
    __syncthreads();
#pragma unroll
    for (int oc = 0; oc < 3; ++oc) {
        float m = s_stat[oc][0], r = s_stat[oc][1];
        s_com[oc][l] = fmaxf((y2[oc] - m) * r * s_w[G5 + oc] + s_w[BB5 + oc], 0.0f);
    }
    __syncthreads();

    // ---- conv6 (3->1) ----
    float a6 = s_w[B6];
#pragma unroll
    for (int ic = 0; ic < 3; ++ic) {
        float c0 = (l > 0)   ? s_com[ic][l - 1] : 0.0f;
        float c1 =             s_com[ic][l];
        float c2 = (l < 511) ? s_com[ic][l + 1] : 0.0f;
        a6 += s_w[W6 + ic * 3] * c0 + s_w[W6 + ic * 3 + 1] * c1 + s_w[W6 + ic * 3 + 2] * c2;
    }
    s_y[0][l] = a6;
    __syncthreads();
    if (wid == 0) {
        float s = 0.f, s2 = 0.f;
#pragma unroll
        for (int j = 0; j < 8; ++j) {
            float v = s_y[0][lane + j * 64];
            s += v; s2 += v * v;
        }
        s = wave_rsum(s); s2 = wave_rsum(s2);
        if (lane == 0) {
            float m = s * (1.0f / 512.0f);
            float var = s2 * (1.0f / 512.0f) - m * m;
            s_stat[0][0] = m; s_stat[0][1] = rsqrtf(var + 1e-5f);
        }
    }
    __syncthreads();
    ws[WSF_XT + l] = fmaxf((a6 - s_stat[0][0]) * s_stat[0][1] * s_w[G6] + s_w[BB6], 0.0f);
}

// =====================================================================
// K4: one GRU layer.  64 blocks x 256 threads; block owns 8 hidden units,
// computes all 6 GEMV rows per unit locally (no grid sync needed).
// =====================================================================
__global__ __launch_bounds__(256) void k_gru(
    const float* __restrict__ wih, const float* __restrict__ whh,
    const float* __restrict__ bih, const float* __restrict__ bhh,
    const float* __restrict__ hstate,
    const float* __restrict__ xt_in, float* __restrict__ xt_out,
    float* __restrict__ hout, int layer)
{
    wih += (size_t)layer * 1536 * 512;
    whh += (size_t)layer * 1536 * 512;
    bih += layer * 1536;
    bhh += layer * 1536;
    const float* hp = hstate + layer * 512;

    const int tid = threadIdx.x, lane = tid & 63, wid = tid >> 6;
    float xq0[4], xq1[4], hq0[4], hq1[4];
#pragma unroll
    for (int j = 0; j < 4; ++j) {
        xq0[j] = xt_in[lane * 4 + j];
        xq1[j] = xt_in[256 + lane * 4 + j];
        hq0[j] = hp[lane * 4 + j];
        hq1[j] = hp[256 + lane * 4 + j];
    }
    __shared__ float s_g[8][6];
    const int i0 = blockIdx.x * 8;
#pragma unroll
    for (int t = 0; t < 2; ++t) {
        const int ii = wid * 2 + t;
        const int i = i0 + ii;
        float a[6] = {0.f, 0.f, 0.f, 0.f, 0.f, 0.f};
#pragma unroll
        for (int g = 0; g < 3; ++g) {
            const float* wr = wih + (size_t)(i + g * 512) * 512;
            f32x4 w0 = *reinterpret_cast<const f32x4*>(wr + lane * 4);
            f32x4 w1 = *reinterpret_cast<const f32x4*>(wr + 256 + lane * 4);
#pragma unroll
            for (int j = 0; j < 4; ++j) a[g] += w0[j] * xq0[j] + w1[j] * xq1[j];
        }
#pragma unroll
        for (int g = 0; g < 3; ++g) {
            const float* wr = whh + (size_t)(i + g * 512) * 512;
            f32x4 w0 = *reinterpret_cast<const f32x4*>(wr + lane * 4);
            f32x4 w1 = *reinterpret_cast<const f32x4*>(wr + 256 + lane * 4);
#pragma unroll
            for (int j = 0; j < 4; ++j) a[3 + g] += w0[j] * hq0[j] + w1[j] * hq1[j];
        }
#pragma unroll
        for (int g = 0; g < 6; ++g) a[g] = wave_rsum(a[g]);
        if (lane == 0) {
#pragma unroll
            for (int g = 0; g < 6; ++g) s_g[ii][g] = a[g];
        }
    }
    __syncthreads();
    if (tid < 8) {
        const int i = i0 + tid;
        float ir = s_g[tid][0] + bih[i];
        float iz = s_g[tid][1] + bih[i + 512];
        float in_ = s_g[tid][2] + bih[i + 1024];
        float hr = s_g[tid][3] + bhh[i];
        float hz = s_g[tid][4] + bhh[i + 512];
        float hn = s_g[tid][5] + bhh[i + 1024];
        float r = sigm(ir + hr);
        float z = sigm(iz + hz);
        float n = tanhf(in_ + r * hn);
        float hprev = hp[i];
        float h = (1.0f - z) * n + z * hprev;
        xt_out[i] = h;
        hout[i] = h;
    }
}

// =====================================================================
// K5: vocab GEMV + per-block online (max, sum-exp).  786 blocks x 256
// =====================================================================
__global__ __launch_bounds__(256) void k_vocab(
    const float* __restrict__ low, const float* __restrict__ lob,
    float* __restrict__ ws)
{
    const int tid = threadIdx.x, lane = tid & 63, wid = tid >> 6;
    float q0[4], q1[4];
#pragma unroll
    for (int j = 0; j < 4; ++j) {
        q0[j] = ws[WSF_XT + 4 * 512 + lane * 4 + j];
        q1[j] = ws[WSF_XT + 4 * 512 + 256 + lane * 4 + j];
    }

    const int row0 = blockIdx.x * 64 + wid * 16;
    float m = -INFINITY, s = 0.0f;
#pragma unroll 4
    for (int r = 0; r < 16; ++r) {
        const int row = row0 + r;
        if (row < NVOCAB) {
            f32x4 w0 = *reinterpret_cast<const f32x4*>(low + (size_t)row * 512 + lane * 4);
            f32x4 w1 = *reinterpret_cast<const f32x4*>(low + (size_t)row * 512 + 256 + lane * 4);
            float a = 0.f;
#pragma unroll
            for (int j = 0; j < 4; ++j) a += w0[j] * q0[j] + w1[j] * q1[j];
            a = wave_rsum(a);
            if (lane == 0) {
                float v = a + lob[row];
                ws[WSF_LOGV + row] = v;
                if (v > m) { s = s * __expf(m - v) + 1.0f; m = v; }
                else       { s += __expf(v - m); }
            }
        }
    }
    __shared__ float sm[4], ss[4];
    if (lane == 0) { sm[wid] = m; ss[wid] = s; }
    __syncthreads();
    if (tid == 0) {
        float M = -INFINITY, S = 0.0f;
#pragma unroll
        for (int w = 0; w < 4; ++w) {
            float mb = sm[w], sb = ss[w];
            if (sb > 0.0f) {
                if (mb > M) { S = S * __expf(M - mb) + sb; M = mb; }
                else        { S += sb * __expf(mb - M); }
            }
        }
        ws[WSF_PM + blockIdx.x] = M;
        ws[WSF_PS + blockIdx.x] = S;
    }
}

// =====================================================================
// K6: combine per-block (max, sum-exp) -> logsumexp.  1 block x 256
// =====================================================================
__global__ __launch_bounds__(256) void k_lse(float* __restrict__ ws, int nb)
{
    __shared__ float sm[256], ss[256];
    const int tid = threadIdx.x;
    float M = -INFINITY, S = 0.0f;
    for (int i = tid; i < nb; i += 256) {
        float mb = ws[WSF_PM + i], sb = ws[WSF_PS + i];
        if (sb > 0.0f) {
            if (mb > M) { S = S * __expf(M - mb) + sb; M = mb; }
            else        { S += sb * __expf(mb - M); }
        }
    }
    sm[tid] = M; ss[tid] = S;
    __syncthreads();
    for (int st = 128; st > 0; st >>= 1) {
        if (tid < st) {
            float mb = sm[tid + st], sb = ss[tid + st];
            if (sb > 0.0f) {
                if (mb > sm[tid]) { ss[tid] = ss[tid] * __expf(sm[tid] - mb) + sb; sm[tid] = mb; }
                else              { ss[tid] += sb * __expf(mb - sm[tid]); }
            }
        }
        __syncthreads();
    }
    if (tid == 0) ws[WSF_LSE] = sm[0] + logf(ss[0]);
}

// =====================================================================
// K7: write log-probs
// =====================================================================
__global__ __launch_bounds__(256) void k_out(
    const float* __restrict__ ws, float* __restrict__ out)
{
    const int i = blockIdx.x * 256 + threadIdx.x;
    if (i < NVOCAB) out[i] = ws[WSF_LOGV + i] - ws[WSF_LSE];
}

// =====================================================================
extern "C" void kernel_launch(void* const* d_in, const int* in_sizes, int n_in,
                              void* d_out, int out_size, void* d_ws, size_t ws_size,
                              hipStream_t stream)
{
    (void)in_sizes; (void)n_in; (void)out_size; (void)ws_size;
    const float* emb     = (const float*)d_in[0];
    const float* conv1_w = (const float*)d_in[1];  const float* conv1_b = (const float*)d_in[2];
    const float* conv2_w = (const float*)d_in[3];  const float* conv2_b = (const float*)d_in[4];
    const float* conv3_w = (const float*)d_in[5];  const float* conv3_b = (const float*)d_in[6];
    const float* conv4_w = (const float*)d_in[7];  const float* conv4_b = (const float*)d_in[8];
    const float* conv5_w = (const float*)d_in[9];  const float* conv5_b = (const float*)d_in[10];
    const float* conv6_w = (const float*)d_in[11]; const float* conv6_b = (const float*)d_in[12];
    const float* bn1_g = (const float*)d_in[13];   const float* bn1_b = (const float*)d_in[14];
    const float* bn2_g = (const float*)d_in[15];   const float* bn2_b = (const float*)d_in[16];
    const float* bn3_g = (const float*)d_in[17];   const float* bn3_b = (const float*)d_in[18];
    const float* bn4_g = (const float*)d_in[19];   const float* bn4_b = (const float*)d_in[20];
    const float* bn5_g = (const float*)d_in[21];   const float* bn5_b = (const float*)d_in[22];
    const float* bn6_g = (const float*)d_in[23];   const float* bn6_b = (const float*)d_in[24];
    const float* att_w = (const float*)d_in[25];   const float* att_b = (const float*)d_in[26];
    const float* gru_wih = (const float*)d_in[27]; const float* gru_whh = (const float*)d_in[28];
    const float* gru_bih = (const float*)d_in[29]; const float* gru_bhh = (const float*)d_in[30];
    const float* lo_w = (const float*)d_in[31];    const float* lo_b = (const float*)d_in[32];
    const float* h_state = (const float*)d_in[33];
    const float* enc = (const float*)d_in[34];
    const int* x = (const int*)d_in[35];

    float* ws = (float*)d_ws;
    float* out = (float*)d_out;

    k_pre<<<1, 512, 0, stream>>>(emb, x, h_state,
        conv1_w, conv1_b, conv2_w, conv2_b, conv3_w, conv3_b,
        bn1_g, bn1_b, bn2_g, bn2_b, bn3_g, bn3_b, ws);
    k_attlogit<<<128, 256, 0, stream>>>(att_w, att_b, ws);
    k_attpv<<<32, 256, 0, stream>>>(enc, ws);
    k_post<<<1, 512, 0, stream>>>(emb, x,
        conv4_w, conv4_b, conv5_w, conv5_b, conv6_w, conv6_b,
        bn4_g, bn4_b, bn5_g, bn5_b, bn6_g, bn6_b, ws);
    for (int l = 0; l < 4; ++l) {
        k_gru<<<64, 256, 0, stream>>>(gru_wih, gru_whh, gru_bih, gru_bhh, h_state,
            ws + WSF_XT + l * 512, ws + WSF_XT + (l + 1) * 512,
            out + NVOCAB + l * 512, l);
    }
    k_vocab<<<NBLK_V, 256, 0, stream>>>(lo_w, lo_b, ws);
    k_lse<<<1, 256, 0, stream>>>(ws, NBLK_V);
    k_out<<<197, 256, 0, stream>>>(ws, out);
}